// Round 3
// baseline (541.668 us; speedup 1.0000x reference)
//
#include <hip/hip_runtime.h>

#define BATCH 256
#define SEQ   512
#define HDIM  768
#define WDIM  25
#define NLAB  42
#define CIN   2354        // 768*2 + 25*2 + 768
#define CINP  2432        // 76 tiles of BK=32 (tail zero-padded in staging)
#define E1W_OFF 1536
#define E2W_OFF 1561
#define CTX_OFF 1586
#define MAXW  10
#define NCHUNK 8          // span split factor; max 64 tokens/block
#define CPW   776         // ctxpart row width: 2 left-pad + 768 + 6 (16B stride)

// ---------------------------------------------------------------------------
// K0: per-(chunk,batch) span partial sums -> ctxpart[c][b][2+j], j = h dim.
// Left pad of 2 floats makes gemm1's float4 ctx reads (k = 1588+4i) aligned.
// grid (8, 256), 192 threads; thread t owns h dims 4t..4t+3.
// ---------------------------------------------------------------------------
__global__ __launch_bounds__(192) void span_partial(
    const float* __restrict__ seq,
    const int* __restrict__ e1p, const int* __restrict__ e2p,
    float* __restrict__ ctxpart) {
  const int b = blockIdx.y;
  const int cidx = blockIdx.x;           // 0..7
  const int t = threadIdx.x;             // 0..191
  const int e1 = e1p[b];
  const int e2 = e2p[b];
  const float4* row4 = (const float4*)(seq + (size_t)b * SEQ * HDIM);

  const int s0 = e1 + 1;
  const int n = max(e2 - s0, 0);
  const int clen = (n + NCHUNK - 1) / NCHUNK;
  const int t0 = s0 + cidx * clen;
  const int t1 = min(t0 + clen, e2);

  float4 acc = make_float4(0.f, 0.f, 0.f, 0.f);
  const float4* p = row4 + (size_t)t0 * 192 + t;
  int tok = t0;
  for (; tok + 4 <= t1; tok += 4) {       // 4 tokens in flight
    float4 v0 = p[0], v1 = p[192], v2 = p[384], v3 = p[576];
    acc.x += (v0.x + v1.x) + (v2.x + v3.x);
    acc.y += (v0.y + v1.y) + (v2.y + v3.y);
    acc.z += (v0.z + v1.z) + (v2.z + v3.z);
    acc.w += (v0.w + v1.w) + (v2.w + v3.w);
    p += 768;
  }
  for (; tok < t1; ++tok) {
    float4 v = *p;
    acc.x += v.x; acc.y += v.y; acc.z += v.z; acc.w += v.w;
    p += 192;
  }
  // always write (zeros when this chunk is empty) — ws is poisoned 0xAA
  float* dst = ctxpart + ((size_t)cidx * BATCH + b) * CPW + 2 + 4 * t;
  *(float2*)(dst)     = make_float2(acc.x, acc.y);
  *(float2*)(dst + 2) = make_float2(acc.z, acc.w);
}

// ---------------------------------------------------------------------------
// A-element gather helpers for the fused GEMM1 (virtual combined[m,k]).
// ---------------------------------------------------------------------------
__device__ __forceinline__ float a_elem(int k,
    const float* __restrict__ re1, const float* __restrict__ re2,
    const float* __restrict__ we1, const float* __restrict__ we2,
    const float* __restrict__ cpm, float inv) {
  if (k < HDIM)     return re1[k];
  if (k < 2*HDIM)   return re2[k - HDIM];
  if (k < E2W_OFF)  return we1[k - E1W_OFF];
  if (k < CTX_OFF)  return we2[k - E2W_OFF];
  if (k < CIN) {
    const int off = 2 + (k - CTX_OFF);
    float s = 0.f;
#pragma unroll
    for (int c = 0; c < NCHUNK; ++c) s += cpm[(size_t)c * BATCH * CPW + off];
    return s * inv;
  }
  return 0.f;
}

__device__ __forceinline__ float4 a_vec(int k,
    const float* __restrict__ re1, const float* __restrict__ re2,
    const float* __restrict__ we1, const float* __restrict__ we2,
    const float* __restrict__ cpm, float inv) {
  // k is a multiple of 4
  if (k + 3 < HDIM) return *(const float4*)(re1 + k);
  if (k >= HDIM && k + 3 < 2*HDIM) return *(const float4*)(re2 + (k - HDIM));
  if (k >= CTX_OFF + 2 && k + 3 < CIN) {     // first vec-k is 1588; off%4==0
    const int off = 2 + (k - CTX_OFF);
    float sx = 0.f, sy = 0.f, sz = 0.f, sw = 0.f;
#pragma unroll
    for (int c = 0; c < NCHUNK; ++c) {
      float4 v = *(const float4*)(cpm + (size_t)c * BATCH * CPW + off);
      sx += v.x; sy += v.y; sz += v.z; sw += v.w;
    }
    return make_float4(sx * inv, sy * inv, sz * inv, sw * inv);
  }
  // boundary tiles (width-emb region, CIN tail): scalar fallback
  return make_float4(a_elem(k,     re1, re2, we1, we2, cpm, inv),
                     a_elem(k + 1, re1, re2, we1, we2, cpm, inv),
                     a_elem(k + 2, re1, re2, we1, we2, cpm, inv),
                     a_elem(k + 3, re1, re2, we1, we2, cpm, inv));
}

// ---------------------------------------------------------------------------
// K1: fused gather + split-K GEMM, double-buffered LDS + register prefetch.
// Virtual A = combined[256 x 2432], B = W1. BM=32,BN=64,BK=32,SPLITK=4.
// grid (12, 8, 4), 256 threads, 2m x 4n per thread.
// ---------------------------------------------------------------------------
#define BM 32
#define BN 64
#define BK 32
#define SPLITK 4
#define KCH 608           // CINP / SPLITK = 19 tiles
#define ASTR 34
#define BSTR 68

__global__ __launch_bounds__(256) void gemm1(
    const float* __restrict__ seq,
    const int* __restrict__ e1p, const int* __restrict__ e2p,
    const int* __restrict__ e1l, const int* __restrict__ e2l,
    const float* __restrict__ wemb,
    const float* __restrict__ ctxpart,
    const float* __restrict__ W1,
    float* __restrict__ hpart) {
  const int nt = blockIdx.x;            // 0..11
  const int mt = blockIdx.y;            // 0..7
  const int ks = blockIdx.z;            // 0..3
  const int tid = threadIdx.x;
  const int k0 = ks * KCH;
  const int m0 = mt * BM;
  const int n0 = nt * BN;

  __shared__ float As[2][BK * ASTR];
  __shared__ float Bs[2][BK * BSTR];

  const int am = tid >> 3;              // staging m row 0..31
  const int ak = (tid & 7) * 4;         // staging k offset 0..28
  const int bk = tid >> 4;              // B k rows bk, bk+16
  const int bn = (tid & 15) * 4;
  const int tx = tid & 15;              // compute col group
  const int ty = tid >> 4;              // compute row group

  // per-thread row context for the gather (fixed across all tiles)
  const int m = m0 + am;
  const int e1 = e1p[m];
  const int e2 = e2p[m];
  int w1i = e1l[m]; w1i = w1i < 0 ? 0 : (w1i > MAXW ? MAXW : w1i);
  int w2i = e2l[m]; w2i = w2i < 0 ? 0 : (w2i > MAXW ? MAXW : w2i);
  const float* re1 = seq + ((size_t)m * SEQ + e1) * HDIM;
  const float* re2 = seq + ((size_t)m * SEQ + e2) * HDIM;
  const float* we1 = wemb + w1i * WDIM;
  const float* we2 = wemb + w2i * WDIM;
  const float* cpm = ctxpart + (size_t)m * CPW;
  const int nspan = max(e2 - e1 - 1, 0);
  const float inv = nspan > 0 ? 1.f / (float)nspan : 0.f;

  const float* Bptr = W1 + (size_t)(k0 + bk) * HDIM + n0 + bn;
  const float4 z4 = make_float4(0.f, 0.f, 0.f, 0.f);
  float4 ar, br0, br1;

  // prologue: tile 0
  ar  = a_vec(k0 + ak, re1, re2, we1, we2, cpm, inv);
  br0 = (k0 + bk < CIN) ? *(const float4*)Bptr : z4;
  br1 = (k0 + bk + 16 < CIN) ? *(const float4*)(Bptr + 16 * HDIM) : z4;
  As[0][(ak + 0) * ASTR + am] = ar.x;
  As[0][(ak + 1) * ASTR + am] = ar.y;
  As[0][(ak + 2) * ASTR + am] = ar.z;
  As[0][(ak + 3) * ASTR + am] = ar.w;
  *(float4*)&Bs[0][bk * BSTR + bn] = br0;
  *(float4*)&Bs[0][(bk + 16) * BSTR + bn] = br1;
  __syncthreads();

  float acc[2][4] = {{0.f,0.f,0.f,0.f},{0.f,0.f,0.f,0.f}};
  const int NT = KCH / BK;              // 19
  int cur = 0;
  for (int t = 0; t < NT; ++t) {
    if (t + 1 < NT) {                   // issue next tile's loads now
      const int kn = k0 + (t + 1) * BK;
      const float* Bp = Bptr + (size_t)(t + 1) * BK * HDIM;
      ar  = a_vec(kn + ak, re1, re2, we1, we2, cpm, inv);
      br0 = (kn + bk < CIN) ? *(const float4*)Bp : z4;
      br1 = (kn + bk + 16 < CIN) ? *(const float4*)(Bp + 16 * HDIM) : z4;
    }
    const float* Asc = As[cur];
    const float* Bsc = Bs[cur];
#pragma unroll
    for (int k = 0; k < BK; ++k) {
      float a0 = Asc[k * ASTR + 2 * ty];
      float a1 = Asc[k * ASTR + 2 * ty + 1];
      float4 bv = *(const float4*)&Bsc[k * BSTR + tx * 4];
      acc[0][0] += a0 * bv.x; acc[0][1] += a0 * bv.y;
      acc[0][2] += a0 * bv.z; acc[0][3] += a0 * bv.w;
      acc[1][0] += a1 * bv.x; acc[1][1] += a1 * bv.y;
      acc[1][2] += a1 * bv.z; acc[1][3] += a1 * bv.w;
    }
    if (t + 1 < NT) {
      __syncthreads();
      int nxt = cur ^ 1;
      As[nxt][(ak + 0) * ASTR + am] = ar.x;
      As[nxt][(ak + 1) * ASTR + am] = ar.y;
      As[nxt][(ak + 2) * ASTR + am] = ar.z;
      As[nxt][(ak + 3) * ASTR + am] = ar.w;
      *(float4*)&Bs[nxt][bk * BSTR + bn] = br0;
      *(float4*)&Bs[nxt][(bk + 16) * BSTR + bn] = br1;
      __syncthreads();
      cur = nxt;
    }
  }

  float* outp = hpart + (size_t)ks * BATCH * HDIM;
#pragma unroll
  for (int i = 0; i < 2; ++i) {
    int mr = m0 + 2 * ty + i;
    float4 v = make_float4(acc[i][0], acc[i][1], acc[i][2], acc[i][3]);
    *(float4*)&outp[(size_t)mr * HDIM + n0 + tx * 4] = v;
  }
}

// ---------------------------------------------------------------------------
// K2: sum SPLITK partials + b1 + ReLU, then [768] x W2[768,42] + b2.
// 256 threads: 6 k-groups x 42 cols + LDS reduce.
// ---------------------------------------------------------------------------
__global__ __launch_bounds__(256) void gemm2(
    const float* __restrict__ hpart,
    const float* __restrict__ b1,
    const float* __restrict__ W2,
    const float* __restrict__ b2,
    float* __restrict__ out) {
  const int m = blockIdx.x;
  const int tid = threadIdx.x;
  __shared__ float hs[HDIM];
  __shared__ float part[6 * NLAB];

  const float* p = hpart + (size_t)m * HDIM;
  const size_t str = (size_t)BATCH * HDIM;
  for (int i = tid; i < HDIM; i += 256) {
    float v = (p[i] + p[i + str]) + (p[i + 2 * str] + p[i + 3 * str]) + b1[i];
    hs[i] = v > 0.f ? v : 0.f;
  }
  __syncthreads();

  if (tid < 252) {
    const int g = tid / NLAB;           // 0..5
    const int c = tid - g * NLAB;       // 0..41
    const int kk0 = g * 128;
    float a = 0.f;
#pragma unroll 8
    for (int j = 0; j < 128; ++j) {
      int k = kk0 + j;
      a += hs[k] * W2[k * NLAB + c];
    }
    part[g * NLAB + c] = a;
  }
  __syncthreads();

  if (tid < NLAB) {
    float r = b2[tid];
#pragma unroll
    for (int g = 0; g < 6; ++g) r += part[g * NLAB + tid];
    out[m * NLAB + tid] = r;
  }
}

// ---------------------------------------------------------------------------
extern "C" void kernel_launch(void* const* d_in, const int* in_sizes, int n_in,
                              void* d_out, int out_size, void* d_ws, size_t ws_size,
                              hipStream_t stream) {
  const float* seq  = (const float*)d_in[0];
  const int*   e1p  = (const int*)d_in[1];
  const int*   e2p  = (const int*)d_in[2];
  const int*   e1l  = (const int*)d_in[3];
  const int*   e2l  = (const int*)d_in[4];
  const float* wemb = (const float*)d_in[5];
  const float* W1   = (const float*)d_in[6];
  const float* b1   = (const float*)d_in[7];
  const float* W2   = (const float*)d_in[8];
  const float* b2   = (const float*)d_in[9];
  float* out = (float*)d_out;

  float* ctxpart = (float*)d_ws;                                  // 8*256*776 f (6.4 MB)
  float* hpart   = ctxpart + (size_t)NCHUNK * BATCH * CPW;        // 4*256*768 f (3.1 MB)

  span_partial<<<dim3(NCHUNK, BATCH), 192, 0, stream>>>(seq, e1p, e2p, ctxpart);
  gemm1<<<dim3(HDIM / BN, BATCH / BM, SPLITK), 256, 0, stream>>>(
      seq, e1p, e2p, e1l, e2l, wemb, ctxpart, W1, hpart);
  gemm2<<<BATCH, 256, 0, stream>>>(hpart, b1, W2, b2, out);
}

// Round 4
// 525.476 us; speedup vs baseline: 1.0308x; 1.0308x over previous
//
#include <hip/hip_runtime.h>

#define BATCH 256
#define SEQ   512
#define HDIM  768
#define WDIM  25
#define NLAB  42
#define CIN   2354        // 768*2 + 25*2 + 768
#define CINP  2432        // K padded to 152*16 (pad zeroed by combine)
#define E1W_OFF 1536
#define E2W_OFF 1561
#define CTX_OFF 1586
#define MAXW  10
#define NCHUNK 8          // span split factor; max 64 tokens/block

// ---------------------------------------------------------------------------
// K0a: per-(chunk,batch) span partial sums + entity reps (cidx==0).
// grid (8, 256), 192 threads; thread t owns float4 column t (768 = 192*4).
// ---------------------------------------------------------------------------
__global__ __launch_bounds__(192) void span_partial(
    const float* __restrict__ seq,
    const int* __restrict__ e1p, const int* __restrict__ e2p,
    float* __restrict__ comb, float* __restrict__ ctxpart) {
  const int b = blockIdx.y;
  const int cidx = blockIdx.x;           // 0..7
  const int t = threadIdx.x;             // 0..191
  const int e1 = e1p[b];
  const int e2 = e2p[b];
  const float4* row4 = (const float4*)(seq + (size_t)b * SEQ * HDIM);

  if (cidx == 0) {  // entity token reps, fully coalesced float4
    float4* crow4 = (float4*)(comb + (size_t)b * CINP);
    crow4[t]       = row4[e1 * 192 + t];
    crow4[192 + t] = row4[e2 * 192 + t];
  }

  const int s0 = e1 + 1;
  const int n = max(e2 - s0, 0);
  const int clen = (n + NCHUNK - 1) / NCHUNK;
  const int t0 = s0 + cidx * clen;
  const int t1 = min(t0 + clen, e2);

  float4 acc = make_float4(0.f, 0.f, 0.f, 0.f);
  const float4* p = row4 + (size_t)t0 * 192 + t;
  int tok = t0;
  for (; tok + 4 <= t1; tok += 4) {       // 4 tokens in flight
    float4 v0 = p[0], v1 = p[192], v2 = p[384], v3 = p[576];
    acc.x += (v0.x + v1.x) + (v2.x + v3.x);
    acc.y += (v0.y + v1.y) + (v2.y + v3.y);
    acc.z += (v0.z + v1.z) + (v2.z + v3.z);
    acc.w += (v0.w + v1.w) + (v2.w + v3.w);
    p += 768;
  }
  for (; tok < t1; ++tok) {
    float4 v = *p;
    acc.x += v.x; acc.y += v.y; acc.z += v.z; acc.w += v.w;
    p += 192;
  }
  float4* cp = (float4*)ctxpart;
  cp[((size_t)cidx * BATCH + b) * (HDIM / 4) + t] = acc;  // 0 if chunk empty
}

// ---------------------------------------------------------------------------
// K0b: combine 8 partials -> ctx; width embeddings; zero the K-pad.
// grid 256, 192 threads.
// ---------------------------------------------------------------------------
__global__ __launch_bounds__(192) void combine(
    const int* __restrict__ e1p, const int* __restrict__ e2p,
    const int* __restrict__ e1l, const int* __restrict__ e2l,
    const float* __restrict__ wemb,
    const float* __restrict__ ctxpart,
    float* __restrict__ comb) {
  const int b = blockIdx.x;
  const int t = threadIdx.x;
  const int n = max(e2p[b] - e1p[b] - 1, 0);
  const float inv = (n > 0) ? 1.f / (float)n : 0.f;
  float* crow = comb + (size_t)b * CINP;

  const float4* cp = (const float4*)ctxpart;
  const size_t base = (size_t)b * (HDIM / 4) + t;
  const size_t str = (size_t)BATCH * (HDIM / 4);
  float sx = 0.f, sy = 0.f, sz = 0.f, sw = 0.f;
#pragma unroll
  for (int c = 0; c < NCHUNK; ++c) {
    float4 v = cp[base + (size_t)c * str];
    sx += v.x; sy += v.y; sz += v.z; sw += v.w;
  }
  // CTX_OFF (1586) is not 16B-aligned within the row -> scalar stores
  crow[CTX_OFF + 4 * t + 0] = sx * inv;
  crow[CTX_OFF + 4 * t + 1] = sy * inv;
  crow[CTX_OFF + 4 * t + 2] = sz * inv;
  crow[CTX_OFF + 4 * t + 3] = sw * inv;

  if (t < WDIM) {
    int w = e1l[b]; w = w < 0 ? 0 : (w > MAXW ? MAXW : w);
    crow[E1W_OFF + t] = wemb[w * WDIM + t];
  } else if (t >= 64 && t < 64 + WDIM) {
    int tt = t - 64;
    int w = e2l[b]; w = w < 0 ? 0 : (w > MAXW ? MAXW : w);
    crow[E2W_OFF + tt] = wemb[w * WDIM + tt];
  }
  if (t < CINP - CIN) crow[CIN + t] = 0.f;   // zero 78-float K pad
}

// ---------------------------------------------------------------------------
// K1: split-K GEMM, double-buffered LDS + register prefetch.
// M=256,N=768,K=2432(pad). BM=64,BN=64,BK=16,SPLITK=8 -> 12*4*8=384 blocks.
// 256 threads, 4m x 4n per thread: 16 FMA per 2 x ds_read_b128 per k-step.
// ---------------------------------------------------------------------------
#define BM 64
#define BN 64
#define BK 16
#define SPLITK 8
#define KCH 304           // CINP / SPLITK = 19 tiles of BK
#define ASTR 68           // multiple of 4 -> b128 rows stay 16B-aligned
#define BSTR 68

__global__ __launch_bounds__(256) void gemm1(
    const float* __restrict__ comb,
    const float* __restrict__ W1,
    float* __restrict__ hpart) {
  const int nt = blockIdx.x;            // 0..11
  const int mt = blockIdx.y;            // 0..3
  const int ks = blockIdx.z;            // 0..7
  const int tid = threadIdx.x;
  const int k0 = ks * KCH;
  const int m0 = mt * BM;
  const int n0 = nt * BN;

  __shared__ float As[2][BK * ASTR];    // transposed As[k][m]
  __shared__ float Bs[2][BK * BSTR];

  // staging: one float4 per thread for each of A and B
  const int am = tid >> 2;              // 0..63 (m row)
  const int ak = (tid & 3) * 4;         // 0,4,8,12 (k offset)
  const int bk = tid >> 4;              // 0..15 (k row)
  const int bn = (tid & 15) * 4;        // n offset
  // compute: rows 4ty..4ty+3, cols 4tx..4tx+3
  const int tx = tid & 15;
  const int ty = tid >> 4;

  const float* Aptr = comb + (size_t)(m0 + am) * CINP + k0 + ak;
  const float* Bptr = W1 + (size_t)(k0 + bk) * HDIM + n0 + bn;
  const float4 z4 = make_float4(0.f, 0.f, 0.f, 0.f);
  float4 ar, br;

  // prologue: tile 0 (A needs no guard: comb K-pad is zeroed)
  ar = *(const float4*)Aptr;
  br = (k0 + bk < CIN) ? *(const float4*)Bptr : z4;
  As[0][(ak + 0) * ASTR + am] = ar.x;
  As[0][(ak + 1) * ASTR + am] = ar.y;
  As[0][(ak + 2) * ASTR + am] = ar.z;
  As[0][(ak + 3) * ASTR + am] = ar.w;
  *(float4*)&Bs[0][bk * BSTR + bn] = br;
  __syncthreads();

  float acc[4][4];
#pragma unroll
  for (int i = 0; i < 4; ++i)
#pragma unroll
    for (int j = 0; j < 4; ++j) acc[i][j] = 0.f;

  const int NT = KCH / BK;              // 19
  int cur = 0;
  for (int t = 0; t < NT; ++t) {
    if (t + 1 < NT) {                   // issue next tile's global loads now
      ar = *(const float4*)(Aptr + (t + 1) * BK);
      br = (k0 + (t + 1) * BK + bk < CIN)
               ? *(const float4*)(Bptr + (size_t)(t + 1) * BK * HDIM) : z4;
    }
    const float* Asc = As[cur];
    const float* Bsc = Bs[cur];
#pragma unroll
    for (int k = 0; k < BK; ++k) {
      float4 av = *(const float4*)&Asc[k * ASTR + 4 * ty];
      float4 bv = *(const float4*)&Bsc[k * BSTR + 4 * tx];
      acc[0][0] += av.x * bv.x; acc[0][1] += av.x * bv.y;
      acc[0][2] += av.x * bv.z; acc[0][3] += av.x * bv.w;
      acc[1][0] += av.y * bv.x; acc[1][1] += av.y * bv.y;
      acc[1][2] += av.y * bv.z; acc[1][3] += av.y * bv.w;
      acc[2][0] += av.z * bv.x; acc[2][1] += av.z * bv.y;
      acc[2][2] += av.z * bv.z; acc[2][3] += av.z * bv.w;
      acc[3][0] += av.w * bv.x; acc[3][1] += av.w * bv.y;
      acc[3][2] += av.w * bv.z; acc[3][3] += av.w * bv.w;
    }
    if (t + 1 < NT) {
      __syncthreads();
      int nxt = cur ^ 1;
      As[nxt][(ak + 0) * ASTR + am] = ar.x;
      As[nxt][(ak + 1) * ASTR + am] = ar.y;
      As[nxt][(ak + 2) * ASTR + am] = ar.z;
      As[nxt][(ak + 3) * ASTR + am] = ar.w;
      *(float4*)&Bs[nxt][bk * BSTR + bn] = br;
      __syncthreads();
      cur = nxt;
    }
  }

  float* outp = hpart + (size_t)ks * BATCH * HDIM;
#pragma unroll
  for (int i = 0; i < 4; ++i) {
    int mr = m0 + 4 * ty + i;
    float4 v = make_float4(acc[i][0], acc[i][1], acc[i][2], acc[i][3]);
    *(float4*)&outp[(size_t)mr * HDIM + n0 + 4 * tx] = v;
  }
}

// ---------------------------------------------------------------------------
// K2: sum SPLITK partials + b1 + ReLU, then [768] x W2[768,42] + b2.
// 256 threads: 6 k-groups x 42 cols + LDS reduce.
// ---------------------------------------------------------------------------
__global__ __launch_bounds__(256) void gemm2(
    const float* __restrict__ hpart,
    const float* __restrict__ b1,
    const float* __restrict__ W2,
    const float* __restrict__ b2,
    float* __restrict__ out) {
  const int m = blockIdx.x;
  const int tid = threadIdx.x;
  __shared__ float hs[HDIM];
  __shared__ float part[6 * NLAB];

  const float* p = hpart + (size_t)m * HDIM;
  const size_t str = (size_t)BATCH * HDIM;
  for (int i = tid; i < HDIM; i += 256) {
    float v = b1[i];
#pragma unroll
    for (int g = 0; g < SPLITK; ++g) v += p[i + g * str];
    hs[i] = v > 0.f ? v : 0.f;
  }
  __syncthreads();

  if (tid < 252) {
    const int g = tid / NLAB;           // 0..5
    const int c = tid - g * NLAB;       // 0..41
    const int kk0 = g * 128;
    float a = 0.f;
#pragma unroll 8
    for (int j = 0; j < 128; ++j) {
      int k = kk0 + j;
      a += hs[k] * W2[k * NLAB + c];
    }
    part[g * NLAB + c] = a;
  }
  __syncthreads();

  if (tid < NLAB) {
    float r = b2[tid];
#pragma unroll
    for (int g = 0; g < 6; ++g) r += part[g * NLAB + tid];
    out[m * NLAB + tid] = r;
  }
}

// ---------------------------------------------------------------------------
extern "C" void kernel_launch(void* const* d_in, const int* in_sizes, int n_in,
                              void* d_out, int out_size, void* d_ws, size_t ws_size,
                              hipStream_t stream) {
  const float* seq  = (const float*)d_in[0];
  const int*   e1p  = (const int*)d_in[1];
  const int*   e2p  = (const int*)d_in[2];
  const int*   e1l  = (const int*)d_in[3];
  const int*   e2l  = (const int*)d_in[4];
  const float* wemb = (const float*)d_in[5];
  const float* W1   = (const float*)d_in[6];
  const float* b1   = (const float*)d_in[7];
  const float* W2   = (const float*)d_in[8];
  const float* b2   = (const float*)d_in[9];
  float* out = (float*)d_out;

  float* comb    = (float*)d_ws;                                  // 256*2432 f (2.5 MB)
  float* ctxpart = comb + (size_t)BATCH * CINP;                   // 8*256*768 f (6.3 MB)
  float* hpart   = ctxpart + (size_t)NCHUNK * BATCH * HDIM;       // 8*256*768 f (6.3 MB)

  span_partial<<<dim3(NCHUNK, BATCH), 192, 0, stream>>>(seq, e1p, e2p, comb, ctxpart);
  combine<<<BATCH, 192, 0, stream>>>(e1p, e2p, e1l, e2l, wemb, ctxpart, comb);
  gemm1<<<dim3(HDIM / BN, BATCH / BM, SPLITK), 256, 0, stream>>>(comb, W1, hpart);
  gemm2<<<BATCH, 256, 0, stream>>>(hpart, b1, W2, b2, out);
}